// Round 5
// baseline (434.307 us; speedup 1.0000x reference)
//
#include <hip/hip_runtime.h>
#include <math.h>

#define HDIM 7168
#define NEXP 256
#define NTOK 8192
#define BM 128
#define BN 128
#define BK 64
#define KS 4
#define KCH (HDIM / KS)      // 1792 source-k per block
#define NR (KCH / BK)        // 28 staging rounds of 64 source-k
#define PITCH 72             // f16 slots per LDS row (64 + 8 pad; 144 B, 16B-aligned)

typedef _Float16 f16x8 __attribute__((ext_vector_type(8)));
typedef float f32x4 __attribute__((ext_vector_type(4)));

__device__ __forceinline__ f16x8 hi8(float4 u, float4 v) {
    f16x8 h;
    h[0] = (_Float16)u.x; h[1] = (_Float16)u.y; h[2] = (_Float16)u.z; h[3] = (_Float16)u.w;
    h[4] = (_Float16)v.x; h[5] = (_Float16)v.y; h[6] = (_Float16)v.z; h[7] = (_Float16)v.w;
    return h;
}
__device__ __forceinline__ f16x8 lo8(float4 u, float4 v, f16x8 h) {
    f16x8 l;
    l[0] = (_Float16)(u.x - (float)h[0]); l[1] = (_Float16)(u.y - (float)h[1]);
    l[2] = (_Float16)(u.z - (float)h[2]); l[3] = (_Float16)(u.w - (float)h[3]);
    l[4] = (_Float16)(v.x - (float)h[4]); l[5] = (_Float16)(v.y - (float)h[5]);
    l[6] = (_Float16)(v.z - (float)h[6]); l[7] = (_Float16)(v.w - (float)h[7]);
    return l;
}

// ---------------------------------------------------------------------------
// One-time (per launch) W conversion: W fp32 -> (Whi, Wlo) f16 planes, x256
// scaled so Wlo stays f16-normal. GEMM epilogue multiplies by 1/256.
// ---------------------------------------------------------------------------
__global__ __launch_bounds__(256)
void wconvert_kernel(const float* __restrict__ W,
                     _Float16* __restrict__ Whi,
                     _Float16* __restrict__ Wlo)
{
    const size_t i8 = ((size_t)blockIdx.x * 256 + threadIdx.x) * 8;
    float4 u = *(const float4*)(W + i8);
    float4 v = *(const float4*)(W + i8 + 4);
    u.x *= 256.0f; u.y *= 256.0f; u.z *= 256.0f; u.w *= 256.0f;
    v.x *= 256.0f; v.y *= 256.0f; v.z *= 256.0f; v.w *= 256.0f;
    f16x8 h = hi8(u, v);
    f16x8 l = lo8(u, v, h);
    *(f16x8*)(Whi + i8) = h;
    *(f16x8*)(Wlo + i8) = l;
}

// ---------------------------------------------------------------------------
// Router GEMM via f16 MFMA 2-term split: logits = hs @ W^T.
// Block 128x128, BK=64, 4 waves in 2x2, wave tile 64x64 = 4x4 tiles of
// 16x16x32 (layouts verified in round 4: A/B frag [idx=lane&15][k=quad*8+j],
// C/D col=lane&15, row=quad*4+reg). 3 products: AhBh + AhBl + AlBh.
// A converted in-kernel; B loaded pre-converted. KSPLIT=4, fp32 atomics.
// LDS rows padded to 72 f16 -> all b128 reads/writes at the 8-cyc floor.
// ---------------------------------------------------------------------------
__global__ __launch_bounds__(256, 2)
void router_gemm_mfma(const float* __restrict__ hs,
                      const _Float16* __restrict__ Whi,
                      const _Float16* __restrict__ Wlo,
                      float* __restrict__ logits)
{
    __shared__ __align__(16) _Float16 Ahi[BM * PITCH];   // 18432 B
    __shared__ __align__(16) _Float16 Alo[BM * PITCH];
    __shared__ __align__(16) _Float16 Bhi[BN * PITCH];
    __shared__ __align__(16) _Float16 Blo[BN * PITCH];   // total 73728 B -> 2 blocks/CU

    const int tid  = threadIdx.x;
    const int lane = tid & 63;
    const int wave = tid >> 6;
    const int bn = blockIdx.x * BN;
    const int bm = blockIdx.y * BM;
    const int kb = blockIdx.z * KCH;

    const int wm = (wave >> 1) * 64;    // wave row band
    const int wn = (wave & 1) * 64;     // wave col band
    const int fm = lane & 15;
    const int quad = lane >> 4;

    // staging: thread -> row tid>>1 (0..127), k-half (tid&1)*32 (f16/f32 units)
    const int srow = tid >> 1;
    const int skh  = (tid & 1) << 5;
    const float*    Ap  = hs  + (size_t)(bm + srow) * HDIM + kb + skh;
    const _Float16* Bph = Whi + (size_t)(bn + srow) * HDIM + kb + skh;
    const _Float16* Bpl = Wlo + (size_t)(bn + srow) * HDIM + kb + skh;

    f32x4 acc[4][4];
#pragma unroll
    for (int i = 0; i < 4; i++)
#pragma unroll
        for (int j = 0; j < 4; j++) acc[i][j] = (f32x4)0.0f;

    // prefetch round 0
    float4 pa[8];
    f16x8 pbh[4], pbl[4];
#pragma unroll
    for (int i = 0; i < 8; i++) pa[i] = *(const float4*)(Ap + i * 4);
#pragma unroll
    for (int i = 0; i < 4; i++) {
        pbh[i] = *(const f16x8*)(Bph + i * 8);
        pbl[i] = *(const f16x8*)(Bpl + i * 8);
    }

    for (int r = 0; r < NR; ++r) {
        __syncthreads();   // previous round's LDS reads complete
        // ---- convert A, store A and B for this round ----
#pragma unroll
        for (int i = 0; i < 4; i++) {
            f16x8 h = hi8(pa[2 * i], pa[2 * i + 1]);
            f16x8 l = lo8(pa[2 * i], pa[2 * i + 1], h);
            *(f16x8*)&Ahi[srow * PITCH + skh + 8 * i] = h;
            *(f16x8*)&Alo[srow * PITCH + skh + 8 * i] = l;
            *(f16x8*)&Bhi[srow * PITCH + skh + 8 * i] = pbh[i];
            *(f16x8*)&Blo[srow * PITCH + skh + 8 * i] = pbl[i];
        }
        __syncthreads();
        // ---- prefetch next round (latency hidden by MFMA phase) ----
        if (r + 1 < NR) {
            const float*    An  = Ap  + (r + 1) * BK;
            const _Float16* Bnh = Bph + (r + 1) * BK;
            const _Float16* Bnl = Bpl + (r + 1) * BK;
#pragma unroll
            for (int i = 0; i < 8; i++) pa[i] = *(const float4*)(An + i * 4);
#pragma unroll
            for (int i = 0; i < 4; i++) {
                pbh[i] = *(const f16x8*)(Bnh + i * 8);
                pbl[i] = *(const f16x8*)(Bnl + i * 8);
            }
        }
        // ---- MFMA: 2 k-steps of 32, 3 products each, 4x4 tiles ----
#pragma unroll
        for (int s = 0; s < 2; s++) {
            const int ko = s * 32 + quad * 8;
            f16x8 af[4], bf[4];
#pragma unroll
            for (int im = 0; im < 4; im++)
                af[im] = *(const f16x8*)&Ahi[(wm + im * 16 + fm) * PITCH + ko];
#pragma unroll
            for (int in_ = 0; in_ < 4; in_++)
                bf[in_] = *(const f16x8*)&Bhi[(wn + in_ * 16 + fm) * PITCH + ko];
            // P1: Ah * Bh
#pragma unroll
            for (int im = 0; im < 4; im++)
#pragma unroll
                for (int in_ = 0; in_ < 4; in_++)
                    acc[im][in_] = __builtin_amdgcn_mfma_f32_16x16x32_f16(af[im], bf[in_], acc[im][in_], 0, 0, 0);
            // P2: Ah * Bl
            {
                f16x8 bl[4];
#pragma unroll
                for (int in_ = 0; in_ < 4; in_++)
                    bl[in_] = *(const f16x8*)&Blo[(wn + in_ * 16 + fm) * PITCH + ko];
#pragma unroll
                for (int im = 0; im < 4; im++)
#pragma unroll
                    for (int in_ = 0; in_ < 4; in_++)
                        acc[im][in_] = __builtin_amdgcn_mfma_f32_16x16x32_f16(af[im], bl[in_], acc[im][in_], 0, 0, 0);
            }
            // P3: Al * Bh
            {
                f16x8 al[4];
#pragma unroll
                for (int im = 0; im < 4; im++)
                    al[im] = *(const f16x8*)&Alo[(wm + im * 16 + fm) * PITCH + ko];
#pragma unroll
                for (int im = 0; im < 4; im++)
#pragma unroll
                    for (int in_ = 0; in_ < 4; in_++)
                        acc[im][in_] = __builtin_amdgcn_mfma_f32_16x16x32_f16(al[im], bf[in_], acc[im][in_], 0, 0, 0);
            }
        }
    }

    // ---- epilogue: undo x256 on B, combine K-splits via atomics ----
#pragma unroll
    for (int im = 0; im < 4; im++) {
#pragma unroll
        for (int in_ = 0; in_ < 4; in_++) {
            const int n = bn + wn + in_ * 16 + fm;
#pragma unroll
            for (int rr = 0; rr < 4; rr++) {
                const int m = bm + wm + im * 16 + quad * 4 + rr;
                unsafeAtomicAdd(&logits[(size_t)m * NEXP + n], acc[im][in_][rr] * 0.00390625f);
            }
        }
    }
}

// ---------------------------------------------------------------------------
// Kernel 2: one wave per token. lane l holds experts 4l..4l+3.
// Replicates jax.lax.top_k semantics exactly: descending, ties -> lower index;
// unselected groups contribute literal 0.0f candidates.
// ---------------------------------------------------------------------------
__global__ __launch_bounds__(256)
void router_topk_kernel(const float* __restrict__ logits,
                        const float* __restrict__ bias,
                        const float* __restrict__ corr,
                        float* __restrict__ out)
{
    const int lane = threadIdx.x & 63;
    const int wave = threadIdx.x >> 6;
    const int t = blockIdx.x * 4 + wave;
    const float* row = logits + (size_t)t * NEXP;
    const int e0 = lane << 2;

    float4 lg = *(const float4*)(row + e0);
    float4 bb = *(const float4*)(bias + e0);
    float4 cc = *(const float4*)(corr + e0);

    float xs[4] = {lg.x + bb.x, lg.y + bb.y, lg.z + bb.z, lg.w + bb.w};
    float cs[4] = {cc.x, cc.y, cc.z, cc.w};
    float s[4], sc[4], mv[4];
#pragma unroll
    for (int i = 0; i < 4; i++) {
        s[i] = 1.0f / (1.0f + expf(-xs[i]));
        sc[i] = s[i] + cs[i];
    }

    // ---- per-group (32 experts = 8 lanes) top-2 sum ----
    float m1 = fmaxf(sc[0], sc[1]);
    float m2 = fminf(sc[0], sc[1]);
    if (sc[2] > m1) { m2 = m1; m1 = sc[2]; } else { m2 = fmaxf(m2, sc[2]); }
    if (sc[3] > m1) { m2 = m1; m1 = sc[3]; } else { m2 = fmaxf(m2, sc[3]); }
#pragma unroll
    for (int off = 1; off <= 4; off <<= 1) {
        float o1 = __shfl_xor(m1, off);
        float o2 = __shfl_xor(m2, off);
        float hi = fmaxf(m1, o1);
        float lo = fminf(m1, o1);
        m1 = hi;
        m2 = fmaxf(lo, fmaxf(m2, o2));
    }
    const float gscore = m1 + m2;

    // ---- broadcast all 8 group scores, compute top-4 group mask ----
    float gs[8];
#pragma unroll
    for (int j = 0; j < 8; j++) gs[j] = __shfl(gscore, j << 3);
    const int g = lane >> 3;
    int rank = 0;
#pragma unroll
    for (int j = 0; j < 8; j++)
        rank += ((gs[j] > gs[g]) || ((gs[j] == gs[g]) && (j < g))) ? 1 : 0;
    const bool sel = (rank < 4);

#pragma unroll
    for (int i = 0; i < 4; i++) mv[i] = sel ? sc[i] : 0.0f;

    // ---- iterative top-8 wave argmax (stable: ties -> lower index) ----
    int oidx[8];
    float ow[8];
    float wsum = 0.0f;
#pragma unroll
    for (int r = 0; r < 8; r++) {
        float bv = mv[0]; int bi = e0;
        if (mv[1] > bv) { bv = mv[1]; bi = e0 + 1; }
        if (mv[2] > bv) { bv = mv[2]; bi = e0 + 2; }
        if (mv[3] > bv) { bv = mv[3]; bi = e0 + 3; }
#pragma unroll
        for (int off = 32; off >= 1; off >>= 1) {
            float ov = __shfl_xor(bv, off);
            int oi = __shfl_xor(bi, off);
            if ((ov > bv) || ((ov == bv) && (oi < bi))) { bv = ov; bi = oi; }
        }
        // all lanes now agree on (bv, bi)
        const int wl = bi >> 2;
        const int slot = bi & 3;
        float sraw = (slot == 0) ? s[0] : (slot == 1) ? s[1] : (slot == 2) ? s[2] : s[3];
        sraw = __shfl(sraw, wl);
        if (lane == wl) {
            if (slot == 0) mv[0] = -1e30f;
            else if (slot == 1) mv[1] = -1e30f;
            else if (slot == 2) mv[2] = -1e30f;
            else mv[3] = -1e30f;
        }
        oidx[r] = bi;
        ow[r] = sraw;
        wsum += sraw;
    }

    if (lane == 0) {
        const float d = wsum + 1e-20f;
        float* oi_p = out + (size_t)t * 8;
        float* ow_p = out + (size_t)NTOK * 8 + (size_t)t * 8;
#pragma unroll
        for (int r = 0; r < 8; r++) {
            oi_p[r] = (float)oidx[r];
            ow_p[r] = (ow[r] / d) * 2.5f;
        }
    }
}

extern "C" void kernel_launch(void* const* d_in, const int* in_sizes, int n_in,
                              void* d_out, int out_size, void* d_ws, size_t ws_size,
                              hipStream_t stream)
{
    const float* hs   = (const float*)d_in[0];   // [8192, 7168]
    const float* W    = (const float*)d_in[1];   // [256, 7168]
    const float* b    = (const float*)d_in[2];   // [256]
    const float* corr = (const float*)d_in[3];   // [256]
    float* out = (float*)d_out;                  // 65536 idx-as-float + 65536 weights

    // ws layout: [0, 8MB) logits fp32 ; [8MB, +3.5MB) Whi ; then Wlo
    float* logits = (float*)d_ws;
    _Float16* Whi = (_Float16*)((char*)d_ws + (size_t)NTOK * NEXP * sizeof(float));
    _Float16* Wlo = Whi + (size_t)NEXP * HDIM;

    // zero the logits accumulator (split-K atomics land here)
    hipMemsetAsync(logits, 0, (size_t)NTOK * NEXP * sizeof(float), stream);

    // convert W -> f16 hi/lo planes (x256 scaled)
    wconvert_kernel<<<(NEXP * HDIM) / (256 * 8), 256, 0, stream>>>(W, Whi, Wlo);

    dim3 g1(NEXP / BN, NTOK / BM, KS);           // (2, 64, 4) -> 512 blocks
    router_gemm_mfma<<<g1, 256, 0, stream>>>(hs, Whi, Wlo, logits);
    router_topk_kernel<<<NTOK / 4, 256, 0, stream>>>(logits, b, corr, out);
}